// Round 17
// baseline (97.828 us; speedup 1.0000x reference)
//
#include <hip/hip_runtime.h>
#include <math.h>
#include <stdint.h>

#define NB 8
#define SEQ 1024
#define DMODEL 512
#define NH 8
#define HD 64
#define R_TOT (NB * SEQ)   // 8192 rows

typedef __attribute__((ext_vector_type(8))) short bf16x8;
typedef __attribute__((ext_vector_type(4))) float f32x4;

__device__ __forceinline__ short f2b(float x) {
    uint32_t u = __float_as_uint(x);
    u += 0x7FFF + ((u >> 16) & 1);          // round-to-nearest-even
    return (short)(u >> 16);
}
__device__ __forceinline__ float b2f(short s) {
    return __uint_as_float(((uint32_t)(uint16_t)s) << 16);
}
__device__ __forceinline__ uint32_t cvtpk_bf16(float lo, float hi) {
    uint32_t r;
    asm("v_cvt_pk_bf16_f32 %0, %1, %2" : "=v"(r) : "v"(lo), "v"(hi));
    return r;
}
// raw hardware exp2 (1 VALU op); -1e30 -> +0 exactly.
__device__ __forceinline__ float exp2_hw(float x) {
    float r;
    asm("v_exp_f32 %0, %1" : "=v"(r) : "v"(x));
    return r;
}

#define GLD_LDS16(g, l)                                                        \
    __builtin_amdgcn_global_load_lds(                                          \
        (const __attribute__((address_space(1))) uint32_t*)(g),                \
        (__attribute__((address_space(3))) uint32_t*)(l), 16, 0, 0)

// T1: bijective chunked XCD swizzle for 3D grids with nwg % 8 == 0
__device__ __forceinline__ void xcd_swizzle(int& bx, int& by, int& bz) {
    const int gx = gridDim.x, gy = gridDim.y;
    const int nwg = gx * gy * gridDim.z;
    int id = (blockIdx.z * gy + blockIdx.y) * gx + blockIdx.x;
    int lg = (id & 7) * (nwg >> 3) + (id >> 3);
    bx = lg % gx;
    int tmp = lg / gx;
    by = tmp % gy;
    bz = tmp / gy;
}

// ---------------- merged fp32 -> bf16 convert (q,k,v + 4 weights) ----------------
#define N4B (R_TOT * DMODEL / 4)
#define N4W (DMODEL * DMODEL / 4)

__global__ __launch_bounds__(256)
void cvt_all(const float* __restrict__ q, const float* __restrict__ k, const float* __restrict__ v,
             const float* __restrict__ wq, const float* __restrict__ wk,
             const float* __restrict__ wv, const float* __restrict__ wo,
             short* dq, short* dk, short* dv, short* dwq, short* dwk, short* dwv, short* dwo)
{
    long i = (long)blockIdx.x * 256 + threadIdx.x;
    const float* s; short* d; long off;
    if (i < (long)N4B)          { s = q;  d = dq;  off = i; }
    else if (i < 2L * N4B)      { s = k;  d = dk;  off = i - N4B; }
    else if (i < 3L * N4B)      { s = v;  d = dv;  off = i - 2L * N4B; }
    else {
        long j = i - 3L * N4B;
        int  w = (int)(j >> 16);
        off = j & (N4W - 1);
        s = (w == 0) ? wq : (w == 1) ? wk : (w == 2) ? wv : wo;
        d = (w == 0) ? dwq : (w == 1) ? dwk : (w == 2) ? dwv : dwo;
    }
    float4 x = ((const float4*)s)[off];
    short4 o;
    o.x = f2b(x.x); o.y = f2b(x.y); o.z = f2b(x.z); o.w = f2b(x.w);
    ((short4*)d)[off] = o;
}

// ============ shared GEMM inner: 128x64 tile, BK=64, dbuf swizzled LDS ============
#define GBM 128
#define GBN 64
#define GBK 64

__device__ __forceinline__ void gemm_core(
    const short* __restrict__ A, const short* __restrict__ Bm,
    const float* __restrict__ bias, const short* __restrict__ resid,
    short* __restrict__ C,
    int N, int m0, int n0, int relu, float oscale,
    short (*As)[GBM * GBK], short (*Bs)[GBN * GBK])
{
    const int tid = threadIdx.x;
    const int l   = tid & 63, w = tid >> 6;
    const int l15 = l & 15,  l4 = l >> 4;
    const int wrow = w >> 1, wcol = w & 1;
    const int K = 512;

    f32x4 acc[4][2] = {};

    auto stageA = [&](int t, int buf) {
        #pragma unroll
        for (int j = 0; j < 4; ++j) {
            int ch  = tid + j * 256;
            int row = ch >> 3;
            int so  = (((ch & 7) * 16) ^ ((row & 7) << 4)) >> 1;
            GLD_LDS16(A + (size_t)(m0 + row) * K + t * GBK + so, &As[buf][ch * 8]);
        }
    };
    auto stageB = [&](int t, int buf) {
        #pragma unroll
        for (int j = 0; j < 2; ++j) {
            int ch  = tid + j * 256;
            int row = ch >> 3;
            int so  = (((ch & 7) * 16) ^ ((row & 7) << 4)) >> 1;
            GLD_LDS16(Bm + (size_t)(n0 + row) * K + t * GBK + so, &Bs[buf][ch * 8]);
        }
    };

    stageA(0, 0); stageB(0, 0);
    __syncthreads();

    for (int t = 0; t < 8; ++t) {
        const int cur = t & 1;
        if (t + 1 < 8) { stageA(t + 1, cur ^ 1); stageB(t + 1, cur ^ 1); }
        __builtin_amdgcn_s_setprio(1);
        #pragma unroll
        for (int kk = 0; kk < 2; ++kk) {
            bf16x8 af[4], bfr[2];
            #pragma unroll
            for (int mi = 0; mi < 4; ++mi) {
                int row = wrow * 64 + mi * 16 + l15;
                af[mi] = *(const bf16x8*)((char*)&As[cur][row * GBK] +
                                          ((kk * 64 + l4 * 16) ^ ((row & 7) << 4)));
            }
            #pragma unroll
            for (int ni = 0; ni < 2; ++ni) {
                int row = wcol * 32 + ni * 16 + l15;
                bfr[ni] = *(const bf16x8*)((char*)&Bs[cur][row * GBK] +
                                           ((kk * 64 + l4 * 16) ^ ((row & 7) << 4)));
            }
            #pragma unroll
            for (int mi = 0; mi < 4; ++mi)
                #pragma unroll
                for (int ni = 0; ni < 2; ++ni)
                    acc[mi][ni] = __builtin_amdgcn_mfma_f32_16x16x32_bf16(af[mi], bfr[ni], acc[mi][ni], 0, 0, 0);
        }
        __builtin_amdgcn_s_setprio(0);
        __syncthreads();
    }

    #pragma unroll
    for (int mi = 0; mi < 4; ++mi) {
        #pragma unroll
        for (int ni = 0; ni < 2; ++ni) {
            int col = n0 + wcol * 32 + ni * 16 + l15;
            float bb = bias ? bias[col] : 0.0f;
            #pragma unroll
            for (int r = 0; r < 4; ++r) {
                int row = m0 + wrow * 64 + mi * 16 + l4 * 4 + r;
                float vv = (acc[mi][ni][r] + bb) * oscale;
                if (relu) vv = fmaxf(vv, 0.0f);
                if (resid) vv += b2f(resid[(size_t)row * N + col]);
                C[(size_t)row * N + col] = f2b(vv);
            }
        }
    }
}

// ---- merged projections: q-proj + k-proj (1024 blocks) + vt (512 blocks) ----
__global__ __launch_bounds__(256)
void proj3(const short* __restrict__ qb, const short* __restrict__ kb,
           const short* __restrict__ vb, const short* __restrict__ wq,
           const short* __restrict__ wv,
           short* __restrict__ qpb, short* __restrict__ vtb, float kscale)
{
    __shared__ short As[2][GBM * GBK];
    __shared__ short Bs[2][GBN * GBK];
    const size_t WSZ  = (size_t)DMODEL * DMODEL;
    const size_t SLOT = (size_t)R_TOT * DMODEL;

    int id = blockIdx.x;
    int lg = (id & 7) * 192 + (id >> 3);

    const short *A, *Bm; short* C; int N, m0, n0; float os = 1.0f;
    if (lg < 1024) {
        int bz  = lg >> 9;
        int rem = lg & 511;
        m0 = (rem >> 3) * GBM;
        n0 = (rem & 7) * GBN;
        A  = bz ? kb : qb;
        Bm = wq + bz * WSZ;
        C  = qpb + bz * SLOT;
        N  = DMODEL;
        os = bz ? kscale : 1.0f;
    } else {
        int r2  = lg - 1024;
        int b   = r2 >> 6;
        int rem = r2 & 63;
        m0 = (rem >> 4) * GBM;
        n0 = (rem & 15) * GBN;
        A  = wv;
        Bm = vb + (long)b * SEQ * DMODEL;
        C  = vtb + (long)b * DMODEL * SEQ;
        N  = SEQ;
    }
    gemm_core(A, Bm, nullptr, nullptr, C, N, m0, n0, 0, os, As, Bs);
}

// ---- out-projection: z = y + relu(y @ Wo^T + bo)  (residual fused) ----
__global__ __launch_bounds__(256)
void outproj(const short* __restrict__ y, const short* __restrict__ wo,
             const float* __restrict__ bias, short* __restrict__ z)
{
    __shared__ short As[2][GBM * GBK];
    __shared__ short Bs[2][GBN * GBK];
    int bx, by, bz;
    xcd_swizzle(bx, by, bz);
    gemm_core(y, wo, bias, y, z, DMODEL, by * GBM, bx * GBN, 1, 1.0f, As, Bs);
}

// ============ flash attention: QBLK=256 (2 q-groups/wave), KVBLK=64, dbuf ============
// Each staged K/V tile feeds 2x the MFMA work (36 MFMA/wave/phase) -> staging and
// barrier overhead per FLOP halves vs QBLK=128. No-max exp2 softmax; masked ->
// v_exp(-1e30)=+0; all-masked row -> osum==0 -> 0. Residual fused: at = qp + attn.
// kp PRE-SCALED by (1/sqrt(512))*log2(e).
__global__ __launch_bounds__(512)
void attn_mfma11(const short* __restrict__ qp, const short* __restrict__ kp,
                 const short* __restrict__ vt, const int* __restrict__ mask,
                 short* __restrict__ attn)
{
    __shared__ short Kb[2][64 * 64];             // K tile, dbuf, swizzled rows
    __shared__ short Vb[2][64 * 64];             // Vt tile, dbuf, swizzled rows
    __shared__ __align__(16) char Ps[8 * 2048];  // per-wave P[16q][64k]
    __shared__ __align__(16) int  Mk[SEQ];       // mask cache
    // total LDS = 52KB

    const int tid = threadIdx.x;
    const int l   = tid & 63, w = tid >> 6;      // w 0..7
    const int l15 = l & 15,  l4 = l >> 4;
    int qb_, h, b;
    xcd_swizzle(qb_, h, b);
    const size_t baseqk = ((size_t)b * SEQ) * DMODEL + h * HD;
    const size_t basev  = ((size_t)b * DMODEL + h * HD) * SEQ;
    const int qrow0 = qb_ * 256 + w * 16 + l15;          // q-group 0
    const int qrow1 = qrow0 + 128;                       // q-group 1

    const int ch  = tid;                         // 512 chunks = one 64x64 bf16 tile
    const int row = ch >> 3;
    const int so  = ((((ch & 7) * 16) ^ ((row & 7) << 4)) >> 1);   // rule-21 pre-swizzle
    const short* kph = kp + baseqk;
    const short* vth = vt + basev;

#define STG(t, bi) do {                                                          \
        GLD_LDS16(kph + (size_t)((t) * 64 + row) * DMODEL + so, &Kb[bi][ch * 8]); \
        GLD_LDS16(vth + (size_t)row * SEQ + (t) * 64 + so,      &Vb[bi][ch * 8]); \
    } while (0)

    // hoisted lane-constant LDS byte offsets ((blk*16+l15)&7 == l15&7)
    const int swk   = (l15 & 7) << 4;
    const int kOff0 = l15 * 128 + ((l4 * 16) ^ swk);
    const int kOff1 = l15 * 128 + ((64 + l4 * 16) ^ swk);
    int pwOff[4];
    #pragma unroll
    for (int c = 0; c < 4; ++c)
        pwOff[c] = (l15 * 128 + c * 32 + l4 * 8) ^ swk;
    const int prOff0 = (l15 * 128 + l4 * 16) ^ swk;
    const int prOff1 = (l15 * 128 + 64 + l4 * 16) ^ swk;

    bf16x8 qf[2][2];
    {
        const short* qr0 = qp + baseqk + (size_t)qrow0 * DMODEL + l4 * 8;
        qf[0][0] = *(const bf16x8*)qr0;
        qf[0][1] = *(const bf16x8*)(qr0 + 32);
        const short* qr1 = qp + baseqk + (size_t)qrow1 * DMODEL + l4 * 8;
        qf[1][0] = *(const bf16x8*)qr1;
        qf[1][1] = *(const bf16x8*)(qr1 + 32);
    }
    const bf16x8 ones = {0x3F80, 0x3F80, 0x3F80, 0x3F80, 0x3F80, 0x3F80, 0x3F80, 0x3F80};

    // prologue: mask -> LDS, stage tile 0
    if (tid < 256) GLD_LDS16(mask + b * SEQ + tid * 4, &Mk[tid * 4]);
    STG(0, 0);
    __syncthreads();

    f32x4 oacc[2][4] = {};
    f32x4 osum[2] = {};
    char* myPs = Ps + w * 2048;

    for (int t = 0; t < 16; ++t) {
        const int cur = t & 1;
        if (t < 15) STG(t + 1, cur ^ 1);         // prefetch hides under 2-group compute

        #pragma unroll
        for (int g = 0; g < 2; ++g) {
            // ---- S^T[k][q] = K.Q^T ----
            f32x4 s[4];
            __builtin_amdgcn_s_setprio(1);
            #pragma unroll
            for (int c = 0; c < 4; ++c) {
                const char* kbase = (const char*)&Kb[cur][0] + c * 2048;
                bf16x8 kf0 = *(const bf16x8*)(kbase + kOff0);
                bf16x8 kf1 = *(const bf16x8*)(kbase + kOff1);
                f32x4 zz = {};
                zz = __builtin_amdgcn_mfma_f32_16x16x32_bf16(kf0, qf[g][0], zz, 0, 0, 0);
                zz = __builtin_amdgcn_mfma_f32_16x16x32_bf16(kf1, qf[g][1], zz, 0, 0, 0);
                s[c] = zz;
            }
            __builtin_amdgcn_s_setprio(0);

            // mask (LDS) -> -1e30, p = 2^s via raw v_exp_f32
            float p[16];
            #pragma unroll
            for (int c = 0; c < 4; ++c) {
                int4 mi = *(const int4*)&Mk[t * 64 + c * 16 + l4 * 4];
                p[c * 4 + 0] = exp2_hw(mi.x ? -1.0e30f : s[c][0]);
                p[c * 4 + 1] = exp2_hw(mi.y ? -1.0e30f : s[c][1]);
                p[c * 4 + 2] = exp2_hw(mi.z ? -1.0e30f : s[c][2]);
                p[c * 4 + 3] = exp2_hw(mi.w ? -1.0e30f : s[c][3]);
            }

            // P pack + exchange (wave-private swizzled LDS, reused per group)
            #pragma unroll
            for (int c = 0; c < 4; ++c) {
                uint2 u;
                u.x = cvtpk_bf16(p[c * 4 + 0], p[c * 4 + 1]);
                u.y = cvtpk_bf16(p[c * 4 + 2], p[c * 4 + 3]);
                *(uint2*)(myPs + pwOff[c]) = u;
            }
            bf16x8 pf0 = *(const bf16x8*)(myPs + prOff0);
            bf16x8 pf1 = *(const bf16x8*)(myPs + prOff1);

            // ---- O^T += Vt.P^T ; row-sum via ones-MFMA ----
            __builtin_amdgcn_s_setprio(1);
            osum[g] = __builtin_amdgcn_mfma_f32_16x16x32_bf16(ones, pf0, osum[g], 0, 0, 0);
            osum[g] = __builtin_amdgcn_mfma_f32_16x16x32_bf16(ones, pf1, osum[g], 0, 0, 0);
            #pragma unroll
            for (int db = 0; db < 4; ++db) {
                const char* vbase = (const char*)&Vb[cur][0] + db * 2048;
                bf16x8 vf0 = *(const bf16x8*)(vbase + kOff0);
                bf16x8 vf1 = *(const bf16x8*)(vbase + kOff1);
                oacc[g][db] = __builtin_amdgcn_mfma_f32_16x16x32_bf16(vf0, pf0, oacc[g][db], 0, 0, 0);
                oacc[g][db] = __builtin_amdgcn_mfma_f32_16x16x32_bf16(vf1, pf1, oacc[g][db], 0, 0, 0);
            }
            __builtin_amdgcn_s_setprio(0);
        }
        __syncthreads();                         // tile t+1 landed + closes buf[cur]
    }
#undef STG

    // at = qp + attn  (residual fused; all-masked row -> inv=0 -> at = qp)
    #pragma unroll
    for (int g = 0; g < 2; ++g) {
        const int qrow = g ? qrow1 : qrow0;
        float inv = (osum[g][0] > 0.0f) ? 1.0f / osum[g][0] : 0.0f;
        #pragma unroll
        for (int db = 0; db < 4; ++db) {
            const size_t eoff = baseqk + (size_t)qrow * DMODEL + db * 16 + l4 * 4;
            short4 qv = *(const short4*)(qp + eoff);
            short4 o;
            o.x = f2b(oacc[g][db][0] * inv + b2f(qv.x));
            o.y = f2b(oacc[g][db][1] * inv + b2f(qv.y));
            o.z = f2b(oacc[g][db][2] * inv + b2f(qv.z));
            o.w = f2b(oacc[g][db][3] * inv + b2f(qv.w));
            *(short4*)(attn + eoff) = o;
        }
    }
}

// ============ LayerNorm, single input: out = LN(X)*g + beta ============
__global__ __launch_bounds__(256)
void ln_one(const short* __restrict__ X, const float* __restrict__ g,
            const float* __restrict__ beta, short* __restrict__ outb,
            float* __restrict__ outf)
{
    const int row  = blockIdx.x * 4 + (threadIdx.x >> 6);
    const int lane = threadIdx.x & 63;
    const size_t off = (size_t)row * DMODEL + lane * 8;
    bf16x8 xv = *(const bf16x8*)&X[off];
    float x[8], s = 0.0f, sq = 0.0f;
    #pragma unroll
    for (int i = 0; i < 8; ++i) {
        x[i] = b2f(xv[i]);
        s += x[i];
        sq += x[i] * x[i];
    }
    #pragma unroll
    for (int o = 1; o < 64; o <<= 1) {
        s  += __shfl_xor(s,  o);
        sq += __shfl_xor(sq, o);
    }
    const float mean = s * (1.0f / DMODEL);
    const float var  = sq * (1.0f / DMODEL) - mean * mean;
    const float rs   = rsqrtf(var + 1e-5f);
    float4 g0 = *(const float4*)&g[lane * 8];
    float4 g1 = *(const float4*)&g[lane * 8 + 4];
    float4 b0 = *(const float4*)&beta[lane * 8];
    float4 b1 = *(const float4*)&beta[lane * 8 + 4];
    float gg[8] = {g0.x, g0.y, g0.z, g0.w, g1.x, g1.y, g1.z, g1.w};
    float bb[8] = {b0.x, b0.y, b0.z, b0.w, b1.x, b1.y, b1.z, b1.w};
    float y[8];
    #pragma unroll
    for (int i = 0; i < 8; ++i)
        y[i] = (x[i] - mean) * rs * gg[i] + bb[i];
    if (outb) {
        bf16x8 o;
        #pragma unroll
        for (int i = 0; i < 8; ++i) o[i] = f2b(y[i]);
        *(bf16x8*)&outb[off] = o;
    } else {
        float4 o0 = {y[0], y[1], y[2], y[3]};
        float4 o1 = {y[4], y[5], y[6], y[7]};
        *(float4*)&outf[off] = o0;
        *(float4*)&outf[off + 4] = o1;
    }
}

// ============ launch ============
extern "C" void kernel_launch(void* const* d_in, const int* in_sizes, int n_in,
                              void* d_out, int out_size, void* d_ws, size_t ws_size,
                              hipStream_t stream)
{
    const float* q    = (const float*)d_in[0];
    const float* k    = (const float*)d_in[1];
    const float* v    = (const float*)d_in[2];
    const int*   mask = (const int*)  d_in[3];
    const float* Wq   = (const float*)d_in[4];
    const float* Wk   = (const float*)d_in[5];
    const float* Wv   = (const float*)d_in[6];
    const float* Wo   = (const float*)d_in[7];
    const float* bo   = (const float*)d_in[8];
    const float* g1   = (const float*)d_in[9];
    const float* b1   = (const float*)d_in[10];
    const float* g2   = (const float*)d_in[11];
    const float* bt2  = (const float*)d_in[12];
    float* out = (float*)d_out;

    short* ws = (short*)d_ws;
    const size_t WSZ  = (size_t)DMODEL * DMODEL;
    const size_t SLOT = (size_t)R_TOT * DMODEL;
    short* wq  = ws;             // wq,wk,wv,wo contiguous
    short* wk  = ws + WSZ;
    short* wv  = ws + 2 * WSZ;
    short* wo  = ws + 3 * WSZ;
    short* qb  = ws + 4 * WSZ;
    short* kb  = qb + SLOT;
    short* vb  = kb + SLOT;
    short* qpb = vb + SLOT;
    short* kpb = qpb + SLOT;     // contiguous after qpb
    short* vtb = kpb + SLOT;     // vt[b][dmodel][SEQ]
    short* at  = qb;             // qb dead after projections
    short* y   = kb;             // kb dead after projections
    short* z   = vb;             // vb dead after projections

    const int nCvtBlocks = (3 * N4B + 4 * N4W) / 256;   // 13312
    cvt_all<<<nCvtBlocks, 256, 0, stream>>>(q, k, v, Wq, Wk, Wv, Wo,
                                            qb, kb, vb, wq, wk, wv, wo);

    // kp pre-scaled by (1/sqrt(512)) * log2(e) for exp2-domain softmax
    const float kscale = 0.06375871530f;

    proj3<<<1536, 256, 0, stream>>>(qb, kb, vb, wq, wv, qpb, vtb, kscale);

    // at = qp + attn (residual fused)
    attn_mfma11<<<dim3(SEQ / 256, NH, NB), 512, 0, stream>>>(qpb, kpb, vtb, mask, at);

    // y = LN(at)
    ln_one<<<R_TOT / 4, 256, 0, stream>>>(at, g1, b1, y, nullptr);

    // z = y + relu(y @ Wo^T + bo)   (residual fused in epilogue)
    outproj<<<dim3(DMODEL / GBN, R_TOT / GBM, 1), 256, 0, stream>>>(y, wo, bo, z);

    // out = LN(z)
    ln_one<<<R_TOT / 4, 256, 0, stream>>>(z, g2, bt2, nullptr, out);
}

// Round 18
// 92.792 us; speedup vs baseline: 1.0543x; 1.0543x over previous
//
#include <hip/hip_runtime.h>
#include <math.h>
#include <stdint.h>

#define NB 8
#define SEQ 1024
#define DMODEL 512
#define NH 8
#define HD 64
#define R_TOT (NB * SEQ)   // 8192 rows

typedef __attribute__((ext_vector_type(8))) short bf16x8;
typedef __attribute__((ext_vector_type(4))) float f32x4;

__device__ __forceinline__ short f2b(float x) {
    uint32_t u = __float_as_uint(x);
    u += 0x7FFF + ((u >> 16) & 1);          // round-to-nearest-even
    return (short)(u >> 16);
}
__device__ __forceinline__ float b2f(short s) {
    return __uint_as_float(((uint32_t)(uint16_t)s) << 16);
}
__device__ __forceinline__ uint32_t cvtpk_bf16(float lo, float hi) {
    uint32_t r;
    asm("v_cvt_pk_bf16_f32 %0, %1, %2" : "=v"(r) : "v"(lo), "v"(hi));
    return r;
}
// raw hardware exp2 (1 VALU op); -1e30 -> +0 exactly.
__device__ __forceinline__ float exp2_hw(float x) {
    float r;
    asm("v_exp_f32 %0, %1" : "=v"(r) : "v"(x));
    return r;
}

#define GLD_LDS16(g, l)                                                        \
    __builtin_amdgcn_global_load_lds(                                          \
        (const __attribute__((address_space(1))) uint32_t*)(g),                \
        (__attribute__((address_space(3))) uint32_t*)(l), 16, 0, 0)

// T1: bijective chunked XCD swizzle for 3D grids with nwg % 8 == 0
__device__ __forceinline__ void xcd_swizzle(int& bx, int& by, int& bz) {
    const int gx = gridDim.x, gy = gridDim.y;
    const int nwg = gx * gy * gridDim.z;
    int id = (blockIdx.z * gy + blockIdx.y) * gx + blockIdx.x;
    int lg = (id & 7) * (nwg >> 3) + (id >> 3);
    bx = lg % gx;
    int tmp = lg / gx;
    by = tmp % gy;
    bz = tmp / gy;
}

// ---------------- merged fp32 -> bf16 convert (q,k,v + 4 weights) ----------------
#define N4B (R_TOT * DMODEL / 4)
#define N4W (DMODEL * DMODEL / 4)

__global__ __launch_bounds__(256)
void cvt_all(const float* __restrict__ q, const float* __restrict__ k, const float* __restrict__ v,
             const float* __restrict__ wq, const float* __restrict__ wk,
             const float* __restrict__ wv, const float* __restrict__ wo,
             short* dq, short* dk, short* dv, short* dwq, short* dwk, short* dwv, short* dwo)
{
    long i = (long)blockIdx.x * 256 + threadIdx.x;
    const float* s; short* d; long off;
    if (i < (long)N4B)          { s = q;  d = dq;  off = i; }
    else if (i < 2L * N4B)      { s = k;  d = dk;  off = i - N4B; }
    else if (i < 3L * N4B)      { s = v;  d = dv;  off = i - 2L * N4B; }
    else {
        long j = i - 3L * N4B;
        int  w = (int)(j >> 16);
        off = j & (N4W - 1);
        s = (w == 0) ? wq : (w == 1) ? wk : (w == 2) ? wv : wo;
        d = (w == 0) ? dwq : (w == 1) ? dwk : (w == 2) ? dwv : dwo;
    }
    float4 x = ((const float4*)s)[off];
    short4 o;
    o.x = f2b(x.x); o.y = f2b(x.y); o.z = f2b(x.z); o.w = f2b(x.w);
    ((short4*)d)[off] = o;
}

// ============ shared GEMM inner: 128x64 tile, BK=64, dbuf swizzled LDS ============
#define GBM 128
#define GBN 64
#define GBK 64

__device__ __forceinline__ void gemm_core(
    const short* __restrict__ A, const short* __restrict__ Bm,
    const float* __restrict__ bias, const short* __restrict__ resid,
    short* __restrict__ C,
    int N, int m0, int n0, int relu, float oscale,
    short (*As)[GBM * GBK], short (*Bs)[GBN * GBK])
{
    const int tid = threadIdx.x;
    const int l   = tid & 63, w = tid >> 6;
    const int l15 = l & 15,  l4 = l >> 4;
    const int wrow = w >> 1, wcol = w & 1;
    const int K = 512;

    f32x4 acc[4][2] = {};

    auto stageA = [&](int t, int buf) {
        #pragma unroll
        for (int j = 0; j < 4; ++j) {
            int ch  = tid + j * 256;
            int row = ch >> 3;
            int so  = (((ch & 7) * 16) ^ ((row & 7) << 4)) >> 1;
            GLD_LDS16(A + (size_t)(m0 + row) * K + t * GBK + so, &As[buf][ch * 8]);
        }
    };
    auto stageB = [&](int t, int buf) {
        #pragma unroll
        for (int j = 0; j < 2; ++j) {
            int ch  = tid + j * 256;
            int row = ch >> 3;
            int so  = (((ch & 7) * 16) ^ ((row & 7) << 4)) >> 1;
            GLD_LDS16(Bm + (size_t)(n0 + row) * K + t * GBK + so, &Bs[buf][ch * 8]);
        }
    };

    stageA(0, 0); stageB(0, 0);
    __syncthreads();

    for (int t = 0; t < 8; ++t) {
        const int cur = t & 1;
        if (t + 1 < 8) { stageA(t + 1, cur ^ 1); stageB(t + 1, cur ^ 1); }
        __builtin_amdgcn_s_setprio(1);
        #pragma unroll
        for (int kk = 0; kk < 2; ++kk) {
            bf16x8 af[4], bfr[2];
            #pragma unroll
            for (int mi = 0; mi < 4; ++mi) {
                int row = wrow * 64 + mi * 16 + l15;
                af[mi] = *(const bf16x8*)((char*)&As[cur][row * GBK] +
                                          ((kk * 64 + l4 * 16) ^ ((row & 7) << 4)));
            }
            #pragma unroll
            for (int ni = 0; ni < 2; ++ni) {
                int row = wcol * 32 + ni * 16 + l15;
                bfr[ni] = *(const bf16x8*)((char*)&Bs[cur][row * GBK] +
                                           ((kk * 64 + l4 * 16) ^ ((row & 7) << 4)));
            }
            #pragma unroll
            for (int mi = 0; mi < 4; ++mi)
                #pragma unroll
                for (int ni = 0; ni < 2; ++ni)
                    acc[mi][ni] = __builtin_amdgcn_mfma_f32_16x16x32_bf16(af[mi], bfr[ni], acc[mi][ni], 0, 0, 0);
        }
        __builtin_amdgcn_s_setprio(0);
        __syncthreads();
    }

    #pragma unroll
    for (int mi = 0; mi < 4; ++mi) {
        #pragma unroll
        for (int ni = 0; ni < 2; ++ni) {
            int col = n0 + wcol * 32 + ni * 16 + l15;
            float bb = bias ? bias[col] : 0.0f;
            #pragma unroll
            for (int r = 0; r < 4; ++r) {
                int row = m0 + wrow * 64 + mi * 16 + l4 * 4 + r;
                float vv = (acc[mi][ni][r] + bb) * oscale;
                if (relu) vv = fmaxf(vv, 0.0f);
                if (resid) vv += b2f(resid[(size_t)row * N + col]);
                C[(size_t)row * N + col] = f2b(vv);
            }
        }
    }
}

// ---- merged projections: q-proj + k-proj (1024 blocks) + vt (512 blocks) ----
__global__ __launch_bounds__(256)
void proj3(const short* __restrict__ qb, const short* __restrict__ kb,
           const short* __restrict__ vb, const short* __restrict__ wq,
           const short* __restrict__ wv,
           short* __restrict__ qpb, short* __restrict__ vtb, float kscale)
{
    __shared__ short As[2][GBM * GBK];
    __shared__ short Bs[2][GBN * GBK];
    const size_t WSZ  = (size_t)DMODEL * DMODEL;
    const size_t SLOT = (size_t)R_TOT * DMODEL;

    int id = blockIdx.x;
    int lg = (id & 7) * 192 + (id >> 3);

    const short *A, *Bm; short* C; int N, m0, n0; float os = 1.0f;
    if (lg < 1024) {
        int bz  = lg >> 9;
        int rem = lg & 511;
        m0 = (rem >> 3) * GBM;
        n0 = (rem & 7) * GBN;
        A  = bz ? kb : qb;
        Bm = wq + bz * WSZ;
        C  = qpb + bz * SLOT;
        N  = DMODEL;
        os = bz ? kscale : 1.0f;
    } else {
        int r2  = lg - 1024;
        int b   = r2 >> 6;
        int rem = r2 & 63;
        m0 = (rem >> 4) * GBM;
        n0 = (rem & 15) * GBN;
        A  = wv;
        Bm = vb + (long)b * SEQ * DMODEL;
        C  = vtb + (long)b * DMODEL * SEQ;
        N  = SEQ;
    }
    gemm_core(A, Bm, nullptr, nullptr, C, N, m0, n0, 0, os, As, Bs);
}

// ---- out-projection: z = y + relu(y @ Wo^T + bo)  (residual fused) ----
__global__ __launch_bounds__(256)
void outproj(const short* __restrict__ y, const short* __restrict__ wo,
             const float* __restrict__ bias, short* __restrict__ z)
{
    __shared__ short As[2][GBM * GBK];
    __shared__ short Bs[2][GBN * GBK];
    int bx, by, bz;
    xcd_swizzle(bx, by, bz);
    gemm_core(y, wo, bias, y, z, DMODEL, by * GBM, bx * GBN, 1, 1.0f, As, Bs);
}

// ============ flash attention: QBLK=128, KVBLK=128, 8 waves, no-max exp2 ============
// kp PRE-SCALED by (1/sqrt(512))*log2(e). Masked -> v_exp(-1e30)=+0; all-masked
// row -> osum==0 -> attn part 0. Output fused with residual: at = qp + attn.
__global__ __launch_bounds__(512)
void attn_mfma9(const short* __restrict__ qp, const short* __restrict__ kp,
                const short* __restrict__ vt, const int* __restrict__ mask,
                short* __restrict__ attn)
{
    __shared__ short Kb[2][2][64 * 64];          // [buf][half][k-row][d], swizzled
    __shared__ short Vb[2][2][64 * 64];          // [buf][half][d-row][k], swizzled
    __shared__ __align__(16) char Ps[8 * 2048];  // per-wave P[16q][64k]

    const int tid = threadIdx.x;
    const int l   = tid & 63, w = tid >> 6;
    const int l15 = l & 15,  l4 = l >> 4;
    int qb_, h, b;
    xcd_swizzle(qb_, h, b);
    const int qrow = qb_ * 128 + w * 16 + l15;
    const size_t baseqk = ((size_t)b * SEQ) * DMODEL + h * HD;
    const size_t basev  = ((size_t)b * DMODEL + h * HD) * SEQ;

    const int ch  = tid;
    const int row = ch >> 3;
    const int so  = ((((ch & 7) * 16) ^ ((row & 7) << 4)) >> 1);
    const short* kph = kp + baseqk;
    const short* vth = vt + basev;
    const int*   mrow = mask + b * SEQ;

#define STAGE(t, bufi) do {                                                                   \
        GLD_LDS16(kph + (size_t)((t) * 128 + row) * DMODEL + so,      &Kb[bufi][0][ch * 8]);  \
        GLD_LDS16(kph + (size_t)((t) * 128 + 64 + row) * DMODEL + so, &Kb[bufi][1][ch * 8]);  \
        GLD_LDS16(vth + (size_t)row * SEQ + (t) * 128 + so,           &Vb[bufi][0][ch * 8]);  \
        GLD_LDS16(vth + (size_t)row * SEQ + (t) * 128 + 64 + so,      &Vb[bufi][1][ch * 8]);  \
    } while (0)

    const int swk   = (l15 & 7) << 4;
    const int kOff0 = l15 * 128 + ((l4 * 16) ^ swk);
    const int kOff1 = l15 * 128 + ((64 + l4 * 16) ^ swk);
    int pwOff[4];
    #pragma unroll
    for (int c = 0; c < 4; ++c)
        pwOff[c] = (l15 * 128 + c * 32 + l4 * 8) ^ swk;
    const int prOff0 = (l15 * 128 + l4 * 16) ^ swk;
    const int prOff1 = (l15 * 128 + 64 + l4 * 16) ^ swk;

    bf16x8 qf0, qf1;
    {
        const short* qr = qp + baseqk + (size_t)qrow * DMODEL + l4 * 8;
        qf0 = *(const bf16x8*)qr;
        qf1 = *(const bf16x8*)(qr + 32);
    }
    const bf16x8 ones = {0x3F80, 0x3F80, 0x3F80, 0x3F80, 0x3F80, 0x3F80, 0x3F80, 0x3F80};

    STAGE(0, 0);
    __syncthreads();

    f32x4 oacc[4] = {};
    f32x4 osum = {};
    char* myPs = Ps + w * 2048;

    for (int t = 0; t < 8; ++t) {
        const int cur = t & 1;
        if (t < 7) STAGE(t + 1, cur ^ 1);

        // prefetch ALL mask words for this phase (latency hides under QK MFMAs)
        int4 mreg[2][4];
        #pragma unroll
        for (int hf = 0; hf < 2; ++hf)
            #pragma unroll
            for (int c = 0; c < 4; ++c)
                mreg[hf][c] = *(const int4*)&mrow[t * 128 + hf * 64 + c * 16 + l4 * 4];

        #pragma unroll
        for (int hf = 0; hf < 2; ++hf) {
            f32x4 s[4];
            __builtin_amdgcn_s_setprio(1);
            #pragma unroll
            for (int c = 0; c < 4; ++c) {
                const char* kbase = (const char*)&Kb[cur][hf][0] + c * 2048;
                bf16x8 kf0 = *(const bf16x8*)(kbase + kOff0);
                bf16x8 kf1 = *(const bf16x8*)(kbase + kOff1);
                f32x4 zz = {};
                zz = __builtin_amdgcn_mfma_f32_16x16x32_bf16(kf0, qf0, zz, 0, 0, 0);
                zz = __builtin_amdgcn_mfma_f32_16x16x32_bf16(kf1, qf1, zz, 0, 0, 0);
                s[c] = zz;
            }
            __builtin_amdgcn_s_setprio(0);

            // mask -> -1e30, p = 2^s via raw v_exp_f32
            float p[16];
            #pragma unroll
            for (int c = 0; c < 4; ++c) {
                int4 mi = mreg[hf][c];
                p[c * 4 + 0] = exp2_hw(mi.x ? -1.0e30f : s[c][0]);
                p[c * 4 + 1] = exp2_hw(mi.y ? -1.0e30f : s[c][1]);
                p[c * 4 + 2] = exp2_hw(mi.z ? -1.0e30f : s[c][2]);
                p[c * 4 + 3] = exp2_hw(mi.w ? -1.0e30f : s[c][3]);
            }

            #pragma unroll
            for (int c = 0; c < 4; ++c) {
                uint2 u;
                u.x = cvtpk_bf16(p[c * 4 + 0], p[c * 4 + 1]);
                u.y = cvtpk_bf16(p[c * 4 + 2], p[c * 4 + 3]);
                *(uint2*)(myPs + pwOff[c]) = u;
            }
            bf16x8 pf0 = *(const bf16x8*)(myPs + prOff0);
            bf16x8 pf1 = *(const bf16x8*)(myPs + prOff1);

            __builtin_amdgcn_s_setprio(1);
            osum = __builtin_amdgcn_mfma_f32_16x16x32_bf16(ones, pf0, osum, 0, 0, 0);
            osum = __builtin_amdgcn_mfma_f32_16x16x32_bf16(ones, pf1, osum, 0, 0, 0);
            #pragma unroll
            for (int db = 0; db < 4; ++db) {
                const char* vbase = (const char*)&Vb[cur][hf][0] + db * 2048;
                bf16x8 vf0 = *(const bf16x8*)(vbase + kOff0);
                bf16x8 vf1 = *(const bf16x8*)(vbase + kOff1);
                oacc[db] = __builtin_amdgcn_mfma_f32_16x16x32_bf16(vf0, pf0, oacc[db], 0, 0, 0);
                oacc[db] = __builtin_amdgcn_mfma_f32_16x16x32_bf16(vf1, pf1, oacc[db], 0, 0, 0);
            }
            __builtin_amdgcn_s_setprio(0);
        }
        __syncthreads();
    }
#undef STAGE

    // at = qp + attn  (residual fused; all-masked row -> inv=0 -> at = qp)
    float inv = (osum[0] > 0.0f) ? 1.0f / osum[0] : 0.0f;
    #pragma unroll
    for (int db = 0; db < 4; ++db) {
        const size_t eoff = baseqk + (size_t)qrow * DMODEL + db * 16 + l4 * 4;
        short4 qv = *(const short4*)(qp + eoff);
        short4 o;
        o.x = f2b(oacc[db][0] * inv + b2f(qv.x));
        o.y = f2b(oacc[db][1] * inv + b2f(qv.y));
        o.z = f2b(oacc[db][2] * inv + b2f(qv.z));
        o.w = f2b(oacc[db][3] * inv + b2f(qv.w));
        *(short4*)(attn + eoff) = o;
    }
}

// ============ LayerNorm, single input: out = LN(X)*g + beta ============
// wave-per-row, short8 loads, shfl-only reduce; 4 rows/block.
__global__ __launch_bounds__(256)
void ln_one(const short* __restrict__ X, const float* __restrict__ g,
            const float* __restrict__ beta, short* __restrict__ outb,
            float* __restrict__ outf)
{
    const int row  = blockIdx.x * 4 + (threadIdx.x >> 6);
    const int lane = threadIdx.x & 63;
    const size_t off = (size_t)row * DMODEL + lane * 8;
    bf16x8 xv = *(const bf16x8*)&X[off];
    float x[8], s = 0.0f, sq = 0.0f;
    #pragma unroll
    for (int i = 0; i < 8; ++i) {
        x[i] = b2f(xv[i]);
        s += x[i];
        sq += x[i] * x[i];
    }
    #pragma unroll
    for (int o = 1; o < 64; o <<= 1) {
        s  += __shfl_xor(s,  o);
        sq += __shfl_xor(sq, o);
    }
    const float mean = s * (1.0f / DMODEL);
    const float var  = sq * (1.0f / DMODEL) - mean * mean;
    const float rs   = rsqrtf(var + 1e-5f);
    float4 g0 = *(const float4*)&g[lane * 8];
    float4 g1 = *(const float4*)&g[lane * 8 + 4];
    float4 b0 = *(const float4*)&beta[lane * 8];
    float4 b1 = *(const float4*)&beta[lane * 8 + 4];
    float gg[8] = {g0.x, g0.y, g0.z, g0.w, g1.x, g1.y, g1.z, g1.w};
    float bb[8] = {b0.x, b0.y, b0.z, b0.w, b1.x, b1.y, b1.z, b1.w};
    float y[8];
    #pragma unroll
    for (int i = 0; i < 8; ++i)
        y[i] = (x[i] - mean) * rs * gg[i] + bb[i];
    if (outb) {
        bf16x8 o;
        #pragma unroll
        for (int i = 0; i < 8; ++i) o[i] = f2b(y[i]);
        *(bf16x8*)&outb[off] = o;
    } else {
        float4 o0 = {y[0], y[1], y[2], y[3]};
        float4 o1 = {y[4], y[5], y[6], y[7]};
        *(float4*)&outf[off] = o0;
        *(float4*)&outf[off + 4] = o1;
    }
}

// ============ launch ============
extern "C" void kernel_launch(void* const* d_in, const int* in_sizes, int n_in,
                              void* d_out, int out_size, void* d_ws, size_t ws_size,
                              hipStream_t stream)
{
    const float* q    = (const float*)d_in[0];
    const float* k    = (const float*)d_in[1];
    const float* v    = (const float*)d_in[2];
    const int*   mask = (const int*)  d_in[3];
    const float* Wq   = (const float*)d_in[4];
    const float* Wk   = (const float*)d_in[5];
    const float* Wv   = (const float*)d_in[6];
    const float* Wo   = (const float*)d_in[7];
    const float* bo   = (const float*)d_in[8];
    const float* g1   = (const float*)d_in[9];
    const float* b1   = (const float*)d_in[10];
    const float* g2   = (const float*)d_in[11];
    const float* bt2  = (const float*)d_in[12];
    float* out = (float*)d_out;

    short* ws = (short*)d_ws;
    const size_t WSZ  = (size_t)DMODEL * DMODEL;
    const size_t SLOT = (size_t)R_TOT * DMODEL;
    short* wq  = ws;             // wq,wk,wv,wo contiguous
    short* wk  = ws + WSZ;
    short* wv  = ws + 2 * WSZ;
    short* wo  = ws + 3 * WSZ;
    short* qb  = ws + 4 * WSZ;
    short* kb  = qb + SLOT;
    short* vb  = kb + SLOT;
    short* qpb = vb + SLOT;
    short* kpb = qpb + SLOT;     // contiguous after qpb
    short* vtb = kpb + SLOT;     // vt[b][dmodel][SEQ]
    short* at  = qb;             // qb dead after projections
    short* y   = kb;             // kb dead after projections
    short* z   = vb;             // vb dead after projections

    const int nCvtBlocks = (3 * N4B + 4 * N4W) / 256;   // 13312
    cvt_all<<<nCvtBlocks, 256, 0, stream>>>(q, k, v, Wq, Wk, Wv, Wo,
                                            qb, kb, vb, wq, wk, wv, wo);

    // kp pre-scaled by (1/sqrt(512)) * log2(e) for exp2-domain softmax
    const float kscale = 0.06375871530f;

    proj3<<<1536, 256, 0, stream>>>(qb, kb, vb, wq, wv, qpb, vtb, kscale);

    // at = qp + attn (residual fused)
    attn_mfma9<<<dim3(SEQ / 128, NH, NB), 512, 0, stream>>>(qpb, kpb, vtb, mask, at);

    // y = LN(at)
    ln_one<<<R_TOT / 4, 256, 0, stream>>>(at, g1, b1, y, nullptr);

    // z = y + relu(y @ Wo^T + bo)   (residual fused in epilogue)
    outproj<<<dim3(DMODEL / GBN, R_TOT / GBM, 1), 256, 0, stream>>>(y, wo, bo, z);

    // out = LN(z)
    ln_one<<<R_TOT / 4, 256, 0, stream>>>(z, g2, bt2, nullptr, out);
}